// Round 1
// 501.487 us; speedup vs baseline: 1.0330x; 1.0330x over previous
//
#include <hip/hip_runtime.h>

// ---------------------------------------------------------------------------
// T5GNNAdapt: LN -> RGCN scatter-mean (2 relations) -> [h0|h1|x] @ [W0;W1;root]
//             + bias -> relu -> @wo -> + residual
// Shapes: B=8,S=1024,D=1024,F=4096,E=262144,N=B*S=8192, K_cat=3072
// R7: gemm1 ported from m97-structure (128^2, 2-barrier, 905 TF plateau) to
// the 256^2 8-phase counted-vmcnt template (T1+T2+T3+T4+T5): 512 thr / 8
// waves (2Mx4N), BK=64, 128 KiB dbuf LDS, per-phase {4-8 ds_read_b128 ||
// 2 GLD16 stage || 16 MFMA}, vmcnt(4) only at phases 4/8, B-frags held in
// registers across the 4 phases of each K-tile. Last 2 K-tiles peeled.
// ---------------------------------------------------------------------------

typedef unsigned short u16;
typedef unsigned int   u32;
typedef __attribute__((ext_vector_type(8))) short bf16x8;
typedef __attribute__((ext_vector_type(4))) float f32x4;
typedef __attribute__((ext_vector_type(2))) float f32x2;

#define E_NUM  262144
#define NNODE  8192
#define NBKT   (2 * NNODE)      // 16384 (rel,dst) buckets
#define DDIM   1024
#define FDIM   4096
#define KCAT   3072
#define LN_EPS 1e-6f

struct alignas(8) u16x4 { u16 x, y, z, w; };

__device__ __forceinline__ u16 f2bf(float f) {
  u32 u = __float_as_uint(f);
  u32 r = u + 0x7fffu + ((u >> 16) & 1u);   // RNE
  return (u16)(r >> 16);
}
__device__ __forceinline__ float bf2f(u16 h) {
  return __uint_as_float(((u32)h) << 16);
}

// ---- fp8 e4m3fn (OCP) encode/decode; HW cvt when available ---------------
__device__ __forceinline__ u32 enc_fp8_1(float f) {
  u32 u = __float_as_uint(f);
  u32 s = u >> 31;
  u32 mag = u & 0x7fffffffu;
  mag = mag + 0x7ffffu + ((mag >> 20) & 1u);          // RNE to 3 mant bits
  if (mag > 0x43e00000u) mag = 0x43e00000u;           // clamp to 448
  u32 e = mag >> 23;
  return (e <= 120u) ? 0u
                     : ((s << 7) | ((e - 120u) << 3) | ((mag >> 20) & 7u));
}

__device__ __forceinline__ u32 pack4_fp8(float a, float b, float c, float d) {
#if __has_builtin(__builtin_amdgcn_cvt_pk_fp8_f32)
  int v = 0;
  v = __builtin_amdgcn_cvt_pk_fp8_f32(a, b, v, false);  // bytes 0,1
  v = __builtin_amdgcn_cvt_pk_fp8_f32(c, d, v, true);   // bytes 2,3
  return (u32)v;
#else
  return enc_fp8_1(a) | (enc_fp8_1(b) << 8) | (enc_fp8_1(c) << 16) |
         (enc_fp8_1(d) << 24);
#endif
}

__device__ __forceinline__ float dec_fp8_1(u32 b) {
  u32 e = (b >> 3) & 15u;
  u32 f = ((b & 0x80u) << 24) | ((e + 120u) << 23) | ((b & 7u) << 20);
  return e ? __uint_as_float(f) : 0.0f;
}

__device__ __forceinline__ void acc4_fp8(float* a, u32 q) {
#if __has_builtin(__builtin_amdgcn_cvt_pk_f32_fp8)
  f32x2 p0 = __builtin_amdgcn_cvt_pk_f32_fp8((int)q, false);
  f32x2 p1 = __builtin_amdgcn_cvt_pk_f32_fp8((int)q, true);
  a[0] += p0.x; a[1] += p0.y; a[2] += p1.x; a[3] += p1.y;
#else
  a[0] += dec_fp8_1(q);       a[1] += dec_fp8_1(q >> 8);
  a[2] += dec_fp8_1(q >> 16); a[3] += dec_fp8_1(q >> 24);
#endif
}

// 16-byte global -> LDS async copy (wave-uniform LDS base + lane*16 layout)
#define GLD16(gp, lp)                                              \
  __builtin_amdgcn_global_load_lds(                                \
      (__attribute__((address_space(1))) u32*)(gp),                \
      (__attribute__((address_space(3))) u32*)(lp), 16, 0, 0)

// ---------------------------------------------------------------------------
// K1: LayerNorm (one-pass). Writes bf16 x into hcat[:, 2048:3072] AND fp8
// copy into dense xq[8192x1024] (aggregation gather input).
// ---------------------------------------------------------------------------
__global__ void ln_kernel(const float* __restrict__ hs,
                          const float* __restrict__ gamma,
                          const float* __restrict__ beta,
                          u16* __restrict__ hcat,
                          u32* __restrict__ xq) {
  const int row = blockIdx.x;
  const int tid = threadIdx.x;
  const float4 v = ((const float4*)(hs + (size_t)row * DDIM))[tid];

  __shared__ float r1[256], r2[256];
  r1[tid] = v.x + v.y + v.z + v.w;
  r2[tid] = v.x * v.x + v.y * v.y + v.z * v.z + v.w * v.w;
  __syncthreads();
  for (int st = 128; st > 0; st >>= 1) {
    if (tid < st) { r1[tid] += r1[tid + st]; r2[tid] += r2[tid + st]; }
    __syncthreads();
  }
  const float mean = r1[0] * (1.0f / DDIM);
  const float var  = r2[0] * (1.0f / DDIM) - mean * mean;
  const float rs   = rsqrtf(var + LN_EPS);

  const int base = tid * 4;
  const float4 g = *(const float4*)(gamma + base);
  const float4 b = *(const float4*)(beta + base);
  const float o0 = (v.x - mean) * rs * g.x + b.x;
  const float o1 = (v.y - mean) * rs * g.y + b.y;
  const float o2 = (v.z - mean) * rs * g.z + b.z;
  const float o3 = (v.w - mean) * rs * g.w + b.w;
  u16x4 o;
  o.x = f2bf(o0); o.y = f2bf(o1); o.z = f2bf(o2); o.w = f2bf(o3);
  *(u16x4*)(hcat + (size_t)row * KCAT + 2048 + base) = o;
  xq[row * 256 + tid] = pack4_fp8(o0, o1, o2, o3);
}

// ---------------------------------------------------------------------------
// K2: f32 [K,N] -> bf16 [N,K] transpose (stitches two sources along K).
// ---------------------------------------------------------------------------
__global__ void cvt_transpose(const float* __restrict__ srcA,
                              const float* __restrict__ srcB,
                              int splitK, int K, int N,
                              u16* __restrict__ dst) {
  __shared__ float tile[32][33];
  const int n0 = blockIdx.x * 32, k0 = blockIdx.y * 32;
  const int tx = threadIdx.x, ty = threadIdx.y;
  for (int i = ty; i < 32; i += 8) {
    const int k = k0 + i;
    const float v = (k < splitK) ? srcA[(size_t)k * N + n0 + tx]
                                 : srcB[(size_t)(k - splitK) * N + n0 + tx];
    tile[i][tx] = v;
  }
  __syncthreads();
  for (int i = ty; i < 32; i += 8) {
    dst[(size_t)(n0 + i) * K + k0 + tx] = f2bf(tile[tx][i]);
  }
}

// ---------------------------------------------------------------------------
// K3a: count edges per (rel,dst) bucket.
// ---------------------------------------------------------------------------
__global__ void count_kernel(const int* __restrict__ edge_index,
                             const int* __restrict__ edge_type,
                             int* __restrict__ cnt) {
  const int e = blockIdx.x * 256 + threadIdx.x;
  const int d = edge_index[E_NUM + e];
  const int r = edge_type[e];
  atomicAdd(&cnt[r * NNODE + d], 1);
}

// ---------------------------------------------------------------------------
// K3b: exclusive prefix sum over 16384 counts (single block, 1024 thr).
// ---------------------------------------------------------------------------
__global__ __launch_bounds__(1024) void scan_kernel(const int* __restrict__ cnt,
                                                    int* __restrict__ off,
                                                    int* __restrict__ cursor) {
  __shared__ int partial[1024];
  const int tid  = threadIdx.x;
  const int base = tid * 16;
  int local[16];
  int s = 0;
#pragma unroll
  for (int i = 0; i < 16; ++i) { local[i] = s; s += cnt[base + i]; }
  partial[tid] = s;
  __syncthreads();
  for (int st = 1; st < 1024; st <<= 1) {
    const int v = (tid >= st) ? partial[tid - st] : 0;
    __syncthreads();
    partial[tid] += v;
    __syncthreads();
  }
  const int pre = (tid == 0) ? 0 : partial[tid - 1];
#pragma unroll
  for (int i = 0; i < 16; ++i) {
    const int o = pre + local[i];
    off[base + i]    = o;
    cursor[base + i] = o;
  }
}

// ---------------------------------------------------------------------------
// K3c: scatter edge SOURCE ids into buckets (4B per edge, not row data).
// ---------------------------------------------------------------------------
__global__ void fill_kernel(const int* __restrict__ edge_index,
                            const int* __restrict__ edge_type,
                            int* __restrict__ cursor,
                            int* __restrict__ bucket_src) {
  const int e = blockIdx.x * 256 + threadIdx.x;
  const int s = edge_index[e];
  const int d = edge_index[E_NUM + e];
  const int r = edge_type[e];
  const int pos = atomicAdd(&cursor[r * NNODE + d], 1);
  bucket_src[pos] = s;
}

// ---------------------------------------------------------------------------
// K4: per-(rel,node) aggregation, fp8 gather. 4 edge-groups x 64 lanes; each
// lane covers 16 cols = one dwordx4 per edge (wave reads full 1KB fp8 row).
// Cross-group reduce via LDS; f32 accumulate; bf16 mean into hcat.
// ---------------------------------------------------------------------------
__global__ __launch_bounds__(256) void aggregate_kernel(
    const int* __restrict__ cnt, const int* __restrict__ off,
    const int* __restrict__ bucket_src, const u32* __restrict__ xq,
    u16* __restrict__ hcat) {
  const int b    = blockIdx.x;            // r*NNODE + node
  const int r    = b >> 13;
  const int node = b & (NNODE - 1);
  const int tid  = threadIdx.x;
  const int g    = tid >> 6;              // edge-group 0..3 (one wave each)
  const int c    = tid & 63;              // col chunk: cols c*16 .. c*16+15
  const int n     = cnt[b];
  const int start = off[b];

  __shared__ int   ids[256];
  __shared__ float red[3 * 1024];
  float a[16] = {};

  for (int c0 = 0; c0 < n; c0 += 256) {
    const int m = min(n - c0, 256);
    __syncthreads();
    if (tid < m) ids[tid] = bucket_src[start + c0 + tid];
    __syncthreads();
    int j = g;
    for (; j + 4 < m; j += 8) {           // unroll 2 (group stride 4)
      const int s0 = ids[j], s1 = ids[j + 4];
      const uint4 x0 = *(const uint4*)(xq + s0 * 256 + c * 4);
      const uint4 x1 = *(const uint4*)(xq + s1 * 256 + c * 4);
      acc4_fp8(a + 0,  x0.x); acc4_fp8(a + 4,  x0.y);
      acc4_fp8(a + 8,  x0.z); acc4_fp8(a + 12, x0.w);
      acc4_fp8(a + 0,  x1.x); acc4_fp8(a + 4,  x1.y);
      acc4_fp8(a + 8,  x1.z); acc4_fp8(a + 12, x1.w);
    }
    for (; j < m; j += 4) {               // remainder
      const int s0 = ids[j];
      const uint4 x0 = *(const uint4*)(xq + s0 * 256 + c * 4);
      acc4_fp8(a + 0,  x0.x); acc4_fp8(a + 4,  x0.y);
      acc4_fp8(a + 8,  x0.z); acc4_fp8(a + 12, x0.w);
    }
  }

  if (g != 0) {
    float* d = red + (g - 1) * 1024 + c * 16;
#pragma unroll
    for (int i = 0; i < 4; ++i)
      *(float4*)(d + i * 4) = make_float4(a[i*4+0], a[i*4+1], a[i*4+2], a[i*4+3]);
  }
  __syncthreads();
  if (g == 0) {
#pragma unroll
    for (int k = 0; k < 3; ++k) {
      const float* d = red + k * 1024 + c * 16;
#pragma unroll
      for (int i = 0; i < 16; ++i) a[i] += d[i];
    }
    const float inv = 1.0f / fmaxf((float)n, 1.0f);
    uint4 o0, o1;
    o0.x = (u32)f2bf(a[0] * inv)  | ((u32)f2bf(a[1] * inv)  << 16);
    o0.y = (u32)f2bf(a[2] * inv)  | ((u32)f2bf(a[3] * inv)  << 16);
    o0.z = (u32)f2bf(a[4] * inv)  | ((u32)f2bf(a[5] * inv)  << 16);
    o0.w = (u32)f2bf(a[6] * inv)  | ((u32)f2bf(a[7] * inv)  << 16);
    o1.x = (u32)f2bf(a[8] * inv)  | ((u32)f2bf(a[9] * inv)  << 16);
    o1.y = (u32)f2bf(a[10] * inv) | ((u32)f2bf(a[11] * inv) << 16);
    o1.z = (u32)f2bf(a[12] * inv) | ((u32)f2bf(a[13] * inv) << 16);
    o1.w = (u32)f2bf(a[14] * inv) | ((u32)f2bf(a[15] * inv) << 16);
    u16* dp = hcat + (size_t)node * KCAT + (size_t)r * DDIM + c * 16;
    *(uint4*)(dp)     = o0;
    *(uint4*)(dp + 8) = o1;
  }
}

// ---------------------------------------------------------------------------
// GEMM1: out1[8192x4096] = bf16(relu(hcat[8192x3072] @ WcatT^T + bias))
// R7: 256x256 tile, BK=64, 512 thr / 8 waves (2Mx4N), 128 KiB dbuf LDS,
// 8-phase counted-vmcnt schedule (T3+T4) + XOR swizzle (T2) + XCD swizzle
// (T1) + setprio (T5). Each phase: 4 (or 12) ds_read_b128 + 2 GLD16 +
// barrier + lgkmcnt(0) + 16 MFMA + barrier; vmcnt(4) only at phases 4/8.
// Staging runs 6 half-pieces ahead: B pieces of tile t+2 overwrite the
// current buffer's B region (register-captured in phase q0); A pieces of
// tile t+1 go to the opposite buffer. Last 2 K-tiles peeled (vmcnt(0)).
// ---------------------------------------------------------------------------

#define MF16(a, b, c) __builtin_amdgcn_mfma_f32_16x16x32_bf16(a, b, c, 0, 0, 0)

#define STAGE_A(t, p, b)                                                   \
  { GLD16(gA0 + (size_t)(t) * 64 + (size_t)(p) * KP,                       \
          &sA[b][(p) * 8192 + lofs0]);                                     \
    GLD16(gA1 + (size_t)(t) * 64 + (size_t)(p) * KP,                       \
          &sA[b][(p) * 8192 + lofs1]); }

#define STAGE_B(t, p, b)                                                   \
  { GLD16(gB0 + (size_t)(t) * 64 + (size_t)(p) * KP,                       \
          &sB[b][(p) * 8192 + lofs0]);                                     \
    GLD16(gB1 + (size_t)(t) * 64 + (size_t)(p) * KP,                       \
          &sB[b][(p) * 8192 + lofs1]); }

#define BVLOAD(b)                                                          \
  { const bf16x8* pB_ = (const bf16x8*)sB[b];                              \
    bv[0][0] = pB_[brow80 + sega0]; bv[0][1] = pB_[brow80 + sega1];        \
    bv[1][0] = pB_[brow81 + sega0]; bv[1][1] = pB_[brow81 + sega1];        \
    bv[2][0] = pB_[brow82 + sega0]; bv[2][1] = pB_[brow82 + sega1];        \
    bv[3][0] = pB_[brow83 + sega0]; bv[3][1] = pB_[brow83 + sega1]; }

#define NOWAIT ((void)0)
#define NOSTAGE ((void)0)
#define VM4 asm volatile("s_waitcnt vmcnt(4)" ::: "memory")
#define VM0 asm volatile("s_waitcnt vmcnt(0)" ::: "memory")

#define PHASE(Q, BUFI, STAGE, ENDW)                                        \
  { const bf16x8* pA_ = (const bf16x8*)sA[BUFI];                           \
    bf16x8 a00 = pA_[arow8[2 * (Q)] + sega0];                              \
    bf16x8 a01 = pA_[arow8[2 * (Q)] + sega1];                              \
    bf16x8 a10 = pA_[arow8[2 * (Q) + 1] + sega0];                          \
    bf16x8 a11 = pA_[arow8[2 * (Q) + 1] + sega1];                          \
    STAGE;                                                                 \
    __builtin_amdgcn_s_barrier();                                          \
    asm volatile("s_waitcnt lgkmcnt(0)" ::: "memory");                     \
    __builtin_amdgcn_s_setprio(1);                                         \
    _Pragma("unroll")                                                      \
    for (int ni = 0; ni < 4; ++ni) {                                       \
      acc[2 * (Q)][ni]     = MF16(a00, bv[ni][0], acc[2 * (Q)][ni]);       \
      acc[2 * (Q)][ni]     = MF16(a01, bv[ni][1], acc[2 * (Q)][ni]);       \
      acc[2 * (Q) + 1][ni] = MF16(a10, bv[ni][0], acc[2 * (Q) + 1][ni]);   \
      acc[2 * (Q) + 1][ni] = MF16(a11, bv[ni][1], acc[2 * (Q) + 1][ni]);   \
    }                                                                      \
    __builtin_amdgcn_s_setprio(0);                                         \
    ENDW;                                                                  \
    __builtin_amdgcn_s_barrier(); }

__global__ __launch_bounds__(512) void gemm1_kernel(
    const u16* __restrict__ A, const u16* __restrict__ Bt,
    const float* __restrict__ bias, u16* __restrict__ obf) {
  const int K = KCAT, N = FDIM;
  const int NT = K / 64;                    // 48 K-tiles
  const size_t KP = (size_t)128 * K;        // piece-1 global row offset
  __shared__ __align__(16) u16 sA[2][16384];  // 64 KB (2 bufs x 256x64 bf16)
  __shared__ __align__(16) u16 sB[2][16384];  // 64 KB

  const int tid  = threadIdx.x;
  const int lane = tid & 63;
  const int wave = tid >> 6;
  const int wr = wave >> 2, wc = wave & 3;    // 2 x 4 wave grid
  const int lr = lane & 15, quad = lane >> 4;

  // XCD-aware swizzle (512 blocks, 512 % 8 == 0 -> simple form is bijective).
  // Consecutive swz share bm -> 16 blocks/XCD reuse one 1.5 MB A panel in L2.
  const int bid = blockIdx.x;
  const int swz = (bid & 7) * 64 + (bid >> 3);
  const int bm = (swz >> 4) * 256;
  const int bn = (swz & 15) * 256;

  // staging addresses: slot s covers 8 bf16 (16 B); row = s>>3 within piece,
  // global segment pre-XOR-swizzled so linear GLD dest + swizzled read match.
  int lofs0, lofs1;
  const u16 *gA0, *gA1, *gB0, *gB1;
  {
    const int s0 = tid,       r0 = s0 >> 3, g0 = (s0 & 7) ^ (r0 & 7);
    const int s1 = tid + 512, r1 = s1 >> 3, g1 = (s1 & 7) ^ (r1 & 7);
    gA0 = A  + (size_t)(bm + r0) * K + g0 * 8;
    gA1 = A  + (size_t)(bm + r1) * K + g1 * 8;
    gB0 = Bt + (size_t)(bn + r0) * K + g0 * 8;
    gB1 = Bt + (size_t)(bn + r1) * K + g1 * 8;
    lofs0 = s0 * 8; lofs1 = s1 * 8;
  }

  // fragment offsets (bf16x8 units): row*8 + ((h*4+quad) ^ (row&7))
  int arow8[8];
#pragma unroll
  for (int mi = 0; mi < 8; ++mi) arow8[mi] = (wr * 128 + mi * 16 + lr) * 8;
  const int brow80 = (wc * 64 +  0 + lr) * 8;
  const int brow81 = (wc * 64 + 16 + lr) * 8;
  const int brow82 = (wc * 64 + 32 + lr) * 8;
  const int brow83 = (wc * 64 + 48 + lr) * 8;
  const int sega0 = quad ^ (lr & 7);
  const int sega1 = (4 + quad) ^ (lr & 7);

  f32x4 acc[8][4] = {};
  bf16x8 bv[4][2];

  // prologue: stage B(0), A(0) -> buf0; B(1) -> buf1 (12 GLDs/thread).
  // vmcnt(4): first 8 (tile 0) landed; Bh(1) still in flight.
  STAGE_B(0, 0, 0) STAGE_B(0, 1, 0)
  STAGE_A(0, 0, 0) STAGE_A(0, 1, 0)
  STAGE_B(1, 0, 1) STAGE_B(1, 1, 1)
  asm volatile("s_waitcnt vmcnt(4)" ::: "memory");
  __builtin_amdgcn_s_barrier();

  for (int tt = 0; tt < NT - 2; tt += 2) {
    // tiles tt (buf0) and tt+1 (buf1)
    PHASE(0, 0, BVLOAD(0); STAGE_A(tt + 1, 0, 1), NOWAIT)
    PHASE(1, 0, STAGE_A(tt + 1, 1, 1), NOWAIT)
    PHASE(2, 0, STAGE_B(tt + 2, 0, 0), NOWAIT)
    PHASE(3, 0, STAGE_B(tt + 2, 1, 0), VM4)
    PHASE(0, 1, BVLOAD(1); STAGE_A(tt + 2, 0, 0), NOWAIT)
    PHASE(1, 1, STAGE_A(tt + 2, 1, 0), NOWAIT)
    PHASE(2, 1, STAGE_B(tt + 3, 0, 1), NOWAIT)
    PHASE(3, 1, STAGE_B(tt + 3, 1, 1), VM4)
  }
  // tail: tiles NT-2 (buf0, stage last A tile) and NT-1 (buf1, compute only)
  PHASE(0, 0, BVLOAD(0); STAGE_A(NT - 1, 0, 1), NOWAIT)
  PHASE(1, 0, STAGE_A(NT - 1, 1, 1), NOWAIT)
  PHASE(2, 0, NOSTAGE, NOWAIT)
  PHASE(3, 0, NOSTAGE, VM0)
  PHASE(0, 1, BVLOAD(1), NOWAIT)
  PHASE(1, 1, NOSTAGE, NOWAIT)
  PHASE(2, 1, NOSTAGE, NOWAIT)
  PHASE(3, 1, NOSTAGE, NOWAIT)

  // epilogue: bias + relu + bf16 store
#pragma unroll
  for (int mi = 0; mi < 8; ++mi) {
#pragma unroll
    for (int ni = 0; ni < 4; ++ni) {
      const int col  = bn + wc * 64 + ni * 16 + lr;
      const int row0 = bm + wr * 128 + mi * 16 + quad * 4;
      const float bb = bias[col];
#pragma unroll
      for (int r = 0; r < 4; ++r) {
        float v = acc[mi][ni][r] + bb;
        v = fmaxf(v, 0.0f);
        obf[(size_t)(row0 + r) * N + col] = f2bf(v);
      }
    }
  }
}

// ---------------------------------------------------------------------------
// GEMM2: out[8192x1024] = resid + out1[8192x4096] @ woT^T
// R6: 64x128 tile (grid 128x8 = 1024 blocks, 4/CU — was 512/2 per CU and
// barrier-drain exposed). BK=64, same XOR swizzle. 24KB LDS. 2x4 acc/wave.
// ---------------------------------------------------------------------------
__global__ __launch_bounds__(256) void gemm2_kernel(
    const u16* __restrict__ A, const u16* __restrict__ Bt,
    const float* __restrict__ resid, float* __restrict__ out) {
  const int K = FDIM, N = DDIM;
  __shared__ __align__(16) u16 sA[64 * 64];    //  8 KB
  __shared__ __align__(16) u16 sB[128 * 64];   // 16 KB
  const int tid  = threadIdx.x;
  const int lane = tid & 63;
  const int wave = tid >> 6;
  const int bm = blockIdx.x * 64;
  const int bn = blockIdx.y * 128;
  const int wm = (wave >> 1) * 32;
  const int wn = (wave & 1) * 64;
  const int lr   = lane & 15;
  const int quad = lane >> 4;

  f32x4 acc[2][4] = {};

  // staging: A 512 slots (2/thread), B 1024 slots (4/thread)
  const u16* gA[2]; u16* lA[2];
#pragma unroll
  for (int i = 0; i < 2; ++i) {
    const int s   = tid + 256 * i;
    const int row = s >> 3;
    const int seg = (s & 7) ^ (row & 7);
    gA[i] = A + (size_t)(bm + row) * K + seg * 8;
    lA[i] = sA + s * 8;
  }
  const u16* gB[4]; u16* lB[4];
#pragma unroll
  for (int i = 0; i < 4; ++i) {
    const int s   = tid + 256 * i;
    const int row = s >> 3;
    const int seg = (s & 7) ^ (row & 7);
    gB[i] = Bt + (size_t)(bn + row) * K + seg * 8;
    lB[i] = sB + s * 8;
  }

  int ai[2][2], bi[4][2];
#pragma unroll
  for (int h = 0; h < 2; ++h) {
#pragma unroll
    for (int mi = 0; mi < 2; ++mi) {
      const int ra = wm + mi * 16 + lr;
      ai[mi][h] = ra * 8 + ((h * 4 + quad) ^ (ra & 7));
    }
#pragma unroll
    for (int ni = 0; ni < 4; ++ni) {
      const int rb = wn + ni * 16 + lr;
      bi[ni][h] = rb * 8 + ((h * 4 + quad) ^ (rb & 7));
    }
  }

  for (int k0 = 0; k0 < K; k0 += 64) {
#pragma unroll
    for (int i = 0; i < 2; ++i) GLD16(gA[i] + k0, lA[i]);
#pragma unroll
    for (int i = 0; i < 4; ++i) GLD16(gB[i] + k0, lB[i]);
    __syncthreads();

    const bf16x8* pA = (const bf16x8*)sA;
    const bf16x8* pB = (const bf16x8*)sB;
#pragma unroll
    for (int h = 0; h < 2; ++h) {
      bf16x8 av[2], bv[4];
#pragma unroll
      for (int mi = 0; mi < 2; ++mi) av[mi] = pA[ai[mi][h]];
#pragma unroll
      for (int ni = 0; ni < 4; ++ni) bv[ni] = pB[bi[ni][h]];
#pragma unroll
      for (int mi = 0; mi < 2; ++mi)
#pragma unroll
        for (int ni = 0; ni < 4; ++ni)
          acc[mi][ni] = __builtin_amdgcn_mfma_f32_16x16x32_bf16(
              av[mi], bv[ni], acc[mi][ni], 0, 0, 0);
    }
    __syncthreads();
  }

#pragma unroll
  for (int mi = 0; mi < 2; ++mi) {
#pragma unroll
    for (int ni = 0; ni < 4; ++ni) {
      const int col  = bn + wn + ni * 16 + lr;
      const int row0 = bm + wm + mi * 16 + quad * 4;
#pragma unroll
      for (int r = 0; r < 4; ++r) {
        const size_t idx = (size_t)(row0 + r) * N + col;
        out[idx] = resid[idx] + acc[mi][ni][r];
      }
    }
  }
}

// ---------------------------------------------------------------------------
// Workspace layout (bytes):
//   hcat       [8192 x 3072] bf16              @ 0          (50331648)
//   WcatT      [4096 x 3072] bf16              @ 50331648   (25165824)
//   woT        [1024 x 4096] bf16              @ 75497472   ( 8388608)
//   out1       [8192 x 4096] bf16              @ 83886080   (67108864)
//     bucket_src [262144] i32 (aliases out1)   @ 83886080   ( 1048576)
//     cnt        [16384] i32                   @ 84934656   (   65536)
//     off        [16384] i32                   @ 85000192   (   65536)
//     cursor     [16384] i32                   @ 85065728   (   65536)
//     xq         [8192 x 1024] fp8             @ 85131264   ( 8388608)
//   (all aliased scratch consumed before GEMM1 writes out1)
// total: 150994944 bytes (144 MB)
// ---------------------------------------------------------------------------
extern "C" void kernel_launch(void* const* d_in, const int* in_sizes, int n_in,
                              void* d_out, int out_size, void* d_ws, size_t ws_size,
                              hipStream_t stream) {
  const float* hs     = (const float*)d_in[0];
  const float* weight = (const float*)d_in[1];   // [2,1024,4096]
  const float* root   = (const float*)d_in[2];   // [1024,4096]
  const float* bias   = (const float*)d_in[3];   // [4096]
  const float* wo     = (const float*)d_in[4];   // [4096,1024]
  const float* gamma  = (const float*)d_in[5];
  const float* beta   = (const float*)d_in[6];
  const int* edge_index = (const int*)d_in[7];   // [2,E]
  const int* edge_type  = (const int*)d_in[8];   // [E]
  float* out = (float*)d_out;

  char* ws = (char*)d_ws;
  u16*   hcat       = (u16*)(ws + 0);
  u16*   WcatT      = (u16*)(ws + 50331648);
  u16*   woT        = (u16*)(ws + 75497472);
  u16*   out1       = (u16*)(ws + 83886080);
  int*   bucket_src = (int*)(ws + 83886080);     // aliases out1 (consumed pre-GEMM1)
  int*   cnt        = (int*)(ws + 84934656);
  int*   off        = (int*)(ws + 85000192);
  int*   cursor     = (int*)(ws + 85065728);
  u32*   xq         = (u32*)(ws + 85131264);     // fp8 x, dense [8192][1024]

  (void)hipMemsetAsync(cnt, 0, 65536, stream);

  ln_kernel<<<NNODE, 256, 0, stream>>>(hs, gamma, beta, hcat, xq);

  cvt_transpose<<<dim3(FDIM / 32, KCAT / 32), dim3(32, 8), 0, stream>>>(
      weight, root, 2048, KCAT, FDIM, WcatT);
  cvt_transpose<<<dim3(DDIM / 32, FDIM / 32), dim3(32, 8), 0, stream>>>(
      wo, wo, FDIM, FDIM, DDIM, woT);

  count_kernel<<<E_NUM / 256, 256, 0, stream>>>(edge_index, edge_type, cnt);
  scan_kernel<<<1, 1024, 0, stream>>>(cnt, off, cursor);
  fill_kernel<<<E_NUM / 256, 256, 0, stream>>>(edge_index, edge_type, cursor, bucket_src);
  aggregate_kernel<<<NBKT, 256, 0, stream>>>(cnt, off, bucket_src, xq, hcat);

  // out1 = relu([h0|h1|x] @ [W0;W1;root] + bias)   [8192 x 4096] bf16
  gemm1_kernel<<<512, 512, 0, stream>>>(hcat, WcatT, bias, out1);

  // out = hs + out1 @ wo                            [8192 x 1024] f32
  gemm2_kernel<<<dim3(8192 / 64, DDIM / 128), 256, 0, stream>>>(
      out1, woT, hs, out);
}

// Round 2
// 474.472 us; speedup vs baseline: 1.0919x; 1.0569x over previous
//
#include <hip/hip_runtime.h>

// ---------------------------------------------------------------------------
// T5GNNAdapt: LN -> RGCN scatter-mean (2 relations) -> [h0|h1|x] @ [W0;W1;root]
//             + bias -> relu -> @wo -> + residual
// Shapes: B=8,S=1024,D=1024,F=4096,E=262144,N=B*S=8192, K_cat=3072
// R7: gemm1 -> 256^2 8-phase counted-vmcnt template (T1..T5): 190.5us,
//     MfmaUtil 47.7%, 1082 TF (was 227.5us / 40.6%).
// R8: gemm2 ported to the same template: BM=256 BN=128 BK=64, 512thr/8waves
//     (4Mx2N, 64x64/wave), 96KB dbuf LDS, 2 phases/K-tile x 16 MFMA,
//     VM2 at K-tile boundaries (B prefetch stays in flight), grid 256 =
//     exactly 1 block/CU, bijective XCD swizzle. gemm1 untouched.
// ---------------------------------------------------------------------------

typedef unsigned short u16;
typedef unsigned int   u32;
typedef __attribute__((ext_vector_type(8))) short bf16x8;
typedef __attribute__((ext_vector_type(4))) float f32x4;
typedef __attribute__((ext_vector_type(2))) float f32x2;

#define E_NUM  262144
#define NNODE  8192
#define NBKT   (2 * NNODE)      // 16384 (rel,dst) buckets
#define DDIM   1024
#define FDIM   4096
#define KCAT   3072
#define LN_EPS 1e-6f

struct alignas(8) u16x4 { u16 x, y, z, w; };

__device__ __forceinline__ u16 f2bf(float f) {
  u32 u = __float_as_uint(f);
  u32 r = u + 0x7fffu + ((u >> 16) & 1u);   // RNE
  return (u16)(r >> 16);
}
__device__ __forceinline__ float bf2f(u16 h) {
  return __uint_as_float(((u32)h) << 16);
}

// ---- fp8 e4m3fn (OCP) encode/decode; HW cvt when available ---------------
__device__ __forceinline__ u32 enc_fp8_1(float f) {
  u32 u = __float_as_uint(f);
  u32 s = u >> 31;
  u32 mag = u & 0x7fffffffu;
  mag = mag + 0x7ffffu + ((mag >> 20) & 1u);          // RNE to 3 mant bits
  if (mag > 0x43e00000u) mag = 0x43e00000u;           // clamp to 448
  u32 e = mag >> 23;
  return (e <= 120u) ? 0u
                     : ((s << 7) | ((e - 120u) << 3) | ((mag >> 20) & 7u));
}

__device__ __forceinline__ u32 pack4_fp8(float a, float b, float c, float d) {
#if __has_builtin(__builtin_amdgcn_cvt_pk_fp8_f32)
  int v = 0;
  v = __builtin_amdgcn_cvt_pk_fp8_f32(a, b, v, false);  // bytes 0,1
  v = __builtin_amdgcn_cvt_pk_fp8_f32(c, d, v, true);   // bytes 2,3
  return (u32)v;
#else
  return enc_fp8_1(a) | (enc_fp8_1(b) << 8) | (enc_fp8_1(c) << 16) |
         (enc_fp8_1(d) << 24);
#endif
}

__device__ __forceinline__ float dec_fp8_1(u32 b) {
  u32 e = (b >> 3) & 15u;
  u32 f = ((b & 0x80u) << 24) | ((e + 120u) << 23) | ((b & 7u) << 20);
  return e ? __uint_as_float(f) : 0.0f;
}

__device__ __forceinline__ void acc4_fp8(float* a, u32 q) {
#if __has_builtin(__builtin_amdgcn_cvt_pk_f32_fp8)
  f32x2 p0 = __builtin_amdgcn_cvt_pk_f32_fp8((int)q, false);
  f32x2 p1 = __builtin_amdgcn_cvt_pk_f32_fp8((int)q, true);
  a[0] += p0.x; a[1] += p0.y; a[2] += p1.x; a[3] += p1.y;
#else
  a[0] += dec_fp8_1(q);       a[1] += dec_fp8_1(q >> 8);
  a[2] += dec_fp8_1(q >> 16); a[3] += dec_fp8_1(q >> 24);
#endif
}

// 16-byte global -> LDS async copy (wave-uniform LDS base + lane*16 layout)
#define GLD16(gp, lp)                                              \
  __builtin_amdgcn_global_load_lds(                                \
      (__attribute__((address_space(1))) u32*)(gp),                \
      (__attribute__((address_space(3))) u32*)(lp), 16, 0, 0)

// ---------------------------------------------------------------------------
// K1: LayerNorm (one-pass). Writes bf16 x into hcat[:, 2048:3072] AND fp8
// copy into dense xq[8192x1024] (aggregation gather input).
// ---------------------------------------------------------------------------
__global__ void ln_kernel(const float* __restrict__ hs,
                          const float* __restrict__ gamma,
                          const float* __restrict__ beta,
                          u16* __restrict__ hcat,
                          u32* __restrict__ xq) {
  const int row = blockIdx.x;
  const int tid = threadIdx.x;
  const float4 v = ((const float4*)(hs + (size_t)row * DDIM))[tid];

  __shared__ float r1[256], r2[256];
  r1[tid] = v.x + v.y + v.z + v.w;
  r2[tid] = v.x * v.x + v.y * v.y + v.z * v.z + v.w * v.w;
  __syncthreads();
  for (int st = 128; st > 0; st >>= 1) {
    if (tid < st) { r1[tid] += r1[tid + st]; r2[tid] += r2[tid + st]; }
    __syncthreads();
  }
  const float mean = r1[0] * (1.0f / DDIM);
  const float var  = r2[0] * (1.0f / DDIM) - mean * mean;
  const float rs   = rsqrtf(var + LN_EPS);

  const int base = tid * 4;
  const float4 g = *(const float4*)(gamma + base);
  const float4 b = *(const float4*)(beta + base);
  const float o0 = (v.x - mean) * rs * g.x + b.x;
  const float o1 = (v.y - mean) * rs * g.y + b.y;
  const float o2 = (v.z - mean) * rs * g.z + b.z;
  const float o3 = (v.w - mean) * rs * g.w + b.w;
  u16x4 o;
  o.x = f2bf(o0); o.y = f2bf(o1); o.z = f2bf(o2); o.w = f2bf(o3);
  *(u16x4*)(hcat + (size_t)row * KCAT + 2048 + base) = o;
  xq[row * 256 + tid] = pack4_fp8(o0, o1, o2, o3);
}

// ---------------------------------------------------------------------------
// K2: f32 [K,N] -> bf16 [N,K] transpose (stitches two sources along K).
// ---------------------------------------------------------------------------
__global__ void cvt_transpose(const float* __restrict__ srcA,
                              const float* __restrict__ srcB,
                              int splitK, int K, int N,
                              u16* __restrict__ dst) {
  __shared__ float tile[32][33];
  const int n0 = blockIdx.x * 32, k0 = blockIdx.y * 32;
  const int tx = threadIdx.x, ty = threadIdx.y;
  for (int i = ty; i < 32; i += 8) {
    const int k = k0 + i;
    const float v = (k < splitK) ? srcA[(size_t)k * N + n0 + tx]
                                 : srcB[(size_t)(k - splitK) * N + n0 + tx];
    tile[i][tx] = v;
  }
  __syncthreads();
  for (int i = ty; i < 32; i += 8) {
    dst[(size_t)(n0 + i) * K + k0 + tx] = f2bf(tile[tx][i]);
  }
}

// ---------------------------------------------------------------------------
// K3a: count edges per (rel,dst) bucket.
// ---------------------------------------------------------------------------
__global__ void count_kernel(const int* __restrict__ edge_index,
                             const int* __restrict__ edge_type,
                             int* __restrict__ cnt) {
  const int e = blockIdx.x * 256 + threadIdx.x;
  const int d = edge_index[E_NUM + e];
  const int r = edge_type[e];
  atomicAdd(&cnt[r * NNODE + d], 1);
}

// ---------------------------------------------------------------------------
// K3b: exclusive prefix sum over 16384 counts (single block, 1024 thr).
// ---------------------------------------------------------------------------
__global__ __launch_bounds__(1024) void scan_kernel(const int* __restrict__ cnt,
                                                    int* __restrict__ off,
                                                    int* __restrict__ cursor) {
  __shared__ int partial[1024];
  const int tid  = threadIdx.x;
  const int base = tid * 16;
  int local[16];
  int s = 0;
#pragma unroll
  for (int i = 0; i < 16; ++i) { local[i] = s; s += cnt[base + i]; }
  partial[tid] = s;
  __syncthreads();
  for (int st = 1; st < 1024; st <<= 1) {
    const int v = (tid >= st) ? partial[tid - st] : 0;
    __syncthreads();
    partial[tid] += v;
    __syncthreads();
  }
  const int pre = (tid == 0) ? 0 : partial[tid - 1];
#pragma unroll
  for (int i = 0; i < 16; ++i) {
    const int o = pre + local[i];
    off[base + i]    = o;
    cursor[base + i] = o;
  }
}

// ---------------------------------------------------------------------------
// K3c: scatter edge SOURCE ids into buckets (4B per edge, not row data).
// ---------------------------------------------------------------------------
__global__ void fill_kernel(const int* __restrict__ edge_index,
                            const int* __restrict__ edge_type,
                            int* __restrict__ cursor,
                            int* __restrict__ bucket_src) {
  const int e = blockIdx.x * 256 + threadIdx.x;
  const int s = edge_index[e];
  const int d = edge_index[E_NUM + e];
  const int r = edge_type[e];
  const int pos = atomicAdd(&cursor[r * NNODE + d], 1);
  bucket_src[pos] = s;
}

// ---------------------------------------------------------------------------
// K4: per-(rel,node) aggregation, fp8 gather. 4 edge-groups x 64 lanes; each
// lane covers 16 cols = one dwordx4 per edge (wave reads full 1KB fp8 row).
// Cross-group reduce via LDS; f32 accumulate; bf16 mean into hcat.
// ---------------------------------------------------------------------------
__global__ __launch_bounds__(256) void aggregate_kernel(
    const int* __restrict__ cnt, const int* __restrict__ off,
    const int* __restrict__ bucket_src, const u32* __restrict__ xq,
    u16* __restrict__ hcat) {
  const int b    = blockIdx.x;            // r*NNODE + node
  const int r    = b >> 13;
  const int node = b & (NNODE - 1);
  const int tid  = threadIdx.x;
  const int g    = tid >> 6;              // edge-group 0..3 (one wave each)
  const int c    = tid & 63;              // col chunk: cols c*16 .. c*16+15
  const int n     = cnt[b];
  const int start = off[b];

  __shared__ int   ids[256];
  __shared__ float red[3 * 1024];
  float a[16] = {};

  for (int c0 = 0; c0 < n; c0 += 256) {
    const int m = min(n - c0, 256);
    __syncthreads();
    if (tid < m) ids[tid] = bucket_src[start + c0 + tid];
    __syncthreads();
    int j = g;
    for (; j + 4 < m; j += 8) {           // unroll 2 (group stride 4)
      const int s0 = ids[j], s1 = ids[j + 4];
      const uint4 x0 = *(const uint4*)(xq + s0 * 256 + c * 4);
      const uint4 x1 = *(const uint4*)(xq + s1 * 256 + c * 4);
      acc4_fp8(a + 0,  x0.x); acc4_fp8(a + 4,  x0.y);
      acc4_fp8(a + 8,  x0.z); acc4_fp8(a + 12, x0.w);
      acc4_fp8(a + 0,  x1.x); acc4_fp8(a + 4,  x1.y);
      acc4_fp8(a + 8,  x1.z); acc4_fp8(a + 12, x1.w);
    }
    for (; j < m; j += 4) {               // remainder
      const int s0 = ids[j];
      const uint4 x0 = *(const uint4*)(xq + s0 * 256 + c * 4);
      acc4_fp8(a + 0,  x0.x); acc4_fp8(a + 4,  x0.y);
      acc4_fp8(a + 8,  x0.z); acc4_fp8(a + 12, x0.w);
    }
  }

  if (g != 0) {
    float* d = red + (g - 1) * 1024 + c * 16;
#pragma unroll
    for (int i = 0; i < 4; ++i)
      *(float4*)(d + i * 4) = make_float4(a[i*4+0], a[i*4+1], a[i*4+2], a[i*4+3]);
  }
  __syncthreads();
  if (g == 0) {
#pragma unroll
    for (int k = 0; k < 3; ++k) {
      const float* d = red + k * 1024 + c * 16;
#pragma unroll
      for (int i = 0; i < 16; ++i) a[i] += d[i];
    }
    const float inv = 1.0f / fmaxf((float)n, 1.0f);
    uint4 o0, o1;
    o0.x = (u32)f2bf(a[0] * inv)  | ((u32)f2bf(a[1] * inv)  << 16);
    o0.y = (u32)f2bf(a[2] * inv)  | ((u32)f2bf(a[3] * inv)  << 16);
    o0.z = (u32)f2bf(a[4] * inv)  | ((u32)f2bf(a[5] * inv)  << 16);
    o0.w = (u32)f2bf(a[6] * inv)  | ((u32)f2bf(a[7] * inv)  << 16);
    o1.x = (u32)f2bf(a[8] * inv)  | ((u32)f2bf(a[9] * inv)  << 16);
    o1.y = (u32)f2bf(a[10] * inv) | ((u32)f2bf(a[11] * inv) << 16);
    o1.z = (u32)f2bf(a[12] * inv) | ((u32)f2bf(a[13] * inv) << 16);
    o1.w = (u32)f2bf(a[14] * inv) | ((u32)f2bf(a[15] * inv) << 16);
    u16* dp = hcat + (size_t)node * KCAT + (size_t)r * DDIM + c * 16;
    *(uint4*)(dp)     = o0;
    *(uint4*)(dp + 8) = o1;
  }
}

// ---------------------------------------------------------------------------
// Shared 8-phase GEMM machinery (expanded in both gemm kernels; all names
// resolve to kernel-local variables at expansion site).
// ---------------------------------------------------------------------------

#define MF16(a, b, c) __builtin_amdgcn_mfma_f32_16x16x32_bf16(a, b, c, 0, 0, 0)

#define STAGE_A(t, p, b)                                                   \
  { GLD16(gA0 + (size_t)(t) * 64 + (size_t)(p) * KP,                       \
          &sA[b][(p) * 8192 + lofs0]);                                     \
    GLD16(gA1 + (size_t)(t) * 64 + (size_t)(p) * KP,                       \
          &sA[b][(p) * 8192 + lofs1]); }

#define STAGE_B(t, p, b)                                                   \
  { GLD16(gB0 + (size_t)(t) * 64 + (size_t)(p) * KP,                       \
          &sB[b][(p) * 8192 + lofs0]);                                     \
    GLD16(gB1 + (size_t)(t) * 64 + (size_t)(p) * KP,                       \
          &sB[b][(p) * 8192 + lofs1]); }

#define BVLOAD(b)                                                          \
  { const bf16x8* pB_ = (const bf16x8*)sB[b];                              \
    bv[0][0] = pB_[brow80 + sega0]; bv[0][1] = pB_[brow80 + sega1];        \
    bv[1][0] = pB_[brow81 + sega0]; bv[1][1] = pB_[brow81 + sega1];        \
    bv[2][0] = pB_[brow82 + sega0]; bv[2][1] = pB_[brow82 + sega1];        \
    bv[3][0] = pB_[brow83 + sega0]; bv[3][1] = pB_[brow83 + sega1]; }

#define NOWAIT ((void)0)
#define NOSTAGE ((void)0)
#define VM4 asm volatile("s_waitcnt vmcnt(4)" ::: "memory")
#define VM2 asm volatile("s_waitcnt vmcnt(2)" ::: "memory")
#define VM0 asm volatile("s_waitcnt vmcnt(0)" ::: "memory")

#define PHASE(Q, BUFI, STAGE, ENDW)                                        \
  { const bf16x8* pA_ = (const bf16x8*)sA[BUFI];                           \
    bf16x8 a00 = pA_[arow8[2 * (Q)] + sega0];                              \
    bf16x8 a01 = pA_[arow8[2 * (Q)] + sega1];                              \
    bf16x8 a10 = pA_[arow8[2 * (Q) + 1] + sega0];                          \
    bf16x8 a11 = pA_[arow8[2 * (Q) + 1] + sega1];                          \
    STAGE;                                                                 \
    __builtin_amdgcn_s_barrier();                                          \
    asm volatile("s_waitcnt lgkmcnt(0)" ::: "memory");                     \
    __builtin_amdgcn_s_setprio(1);                                         \
    _Pragma("unroll")                                                      \
    for (int ni = 0; ni < 4; ++ni) {                                       \
      acc[2 * (Q)][ni]     = MF16(a00, bv[ni][0], acc[2 * (Q)][ni]);       \
      acc[2 * (Q)][ni]     = MF16(a01, bv[ni][1], acc[2 * (Q)][ni]);       \
      acc[2 * (Q) + 1][ni] = MF16(a10, bv[ni][0], acc[2 * (Q) + 1][ni]);   \
      acc[2 * (Q) + 1][ni] = MF16(a11, bv[ni][1], acc[2 * (Q) + 1][ni]);   \
    }                                                                      \
    __builtin_amdgcn_s_setprio(0);                                         \
    ENDW;                                                                  \
    __builtin_amdgcn_s_barrier(); }

// ---------------------------------------------------------------------------
// GEMM1: out1[8192x4096] = bf16(relu(hcat[8192x3072] @ WcatT^T + bias))
// 256x256 tile, BK=64, 512 thr / 8 waves (2Mx4N), 128 KiB dbuf LDS,
// 8-phase counted-vmcnt schedule; vmcnt(4) only at phases 4/8. (R7: 190us)
// ---------------------------------------------------------------------------
__global__ __launch_bounds__(512) void gemm1_kernel(
    const u16* __restrict__ A, const u16* __restrict__ Bt,
    const float* __restrict__ bias, u16* __restrict__ obf) {
  const int K = KCAT, N = FDIM;
  const int NT = K / 64;                    // 48 K-tiles
  const size_t KP = (size_t)128 * K;        // piece-1 global row offset
  __shared__ __align__(16) u16 sA[2][16384];  // 64 KB (2 bufs x 256x64 bf16)
  __shared__ __align__(16) u16 sB[2][16384];  // 64 KB

  const int tid  = threadIdx.x;
  const int lane = tid & 63;
  const int wave = tid >> 6;
  const int wr = wave >> 2, wc = wave & 3;    // 2 x 4 wave grid
  const int lr = lane & 15, quad = lane >> 4;

  const int bid = blockIdx.x;
  const int swz = (bid & 7) * 64 + (bid >> 3);
  const int bm = (swz >> 4) * 256;
  const int bn = (swz & 15) * 256;

  int lofs0, lofs1;
  const u16 *gA0, *gA1, *gB0, *gB1;
  {
    const int s0 = tid,       r0 = s0 >> 3, g0 = (s0 & 7) ^ (r0 & 7);
    const int s1 = tid + 512, r1 = s1 >> 3, g1 = (s1 & 7) ^ (r1 & 7);
    gA0 = A  + (size_t)(bm + r0) * K + g0 * 8;
    gA1 = A  + (size_t)(bm + r1) * K + g1 * 8;
    gB0 = Bt + (size_t)(bn + r0) * K + g0 * 8;
    gB1 = Bt + (size_t)(bn + r1) * K + g1 * 8;
    lofs0 = s0 * 8; lofs1 = s1 * 8;
  }

  int arow8[8];
#pragma unroll
  for (int mi = 0; mi < 8; ++mi) arow8[mi] = (wr * 128 + mi * 16 + lr) * 8;
  const int brow80 = (wc * 64 +  0 + lr) * 8;
  const int brow81 = (wc * 64 + 16 + lr) * 8;
  const int brow82 = (wc * 64 + 32 + lr) * 8;
  const int brow83 = (wc * 64 + 48 + lr) * 8;
  const int sega0 = quad ^ (lr & 7);
  const int sega1 = (4 + quad) ^ (lr & 7);

  f32x4 acc[8][4] = {};
  bf16x8 bv[4][2];

  STAGE_B(0, 0, 0) STAGE_B(0, 1, 0)
  STAGE_A(0, 0, 0) STAGE_A(0, 1, 0)
  STAGE_B(1, 0, 1) STAGE_B(1, 1, 1)
  asm volatile("s_waitcnt vmcnt(4)" ::: "memory");
  __builtin_amdgcn_s_barrier();

  for (int tt = 0; tt < NT - 2; tt += 2) {
    PHASE(0, 0, BVLOAD(0); STAGE_A(tt + 1, 0, 1), NOWAIT)
    PHASE(1, 0, STAGE_A(tt + 1, 1, 1), NOWAIT)
    PHASE(2, 0, STAGE_B(tt + 2, 0, 0), NOWAIT)
    PHASE(3, 0, STAGE_B(tt + 2, 1, 0), VM4)
    PHASE(0, 1, BVLOAD(1); STAGE_A(tt + 2, 0, 0), NOWAIT)
    PHASE(1, 1, STAGE_A(tt + 2, 1, 0), NOWAIT)
    PHASE(2, 1, STAGE_B(tt + 3, 0, 1), NOWAIT)
    PHASE(3, 1, STAGE_B(tt + 3, 1, 1), VM4)
  }
  PHASE(0, 0, BVLOAD(0); STAGE_A(NT - 1, 0, 1), NOWAIT)
  PHASE(1, 0, STAGE_A(NT - 1, 1, 1), NOWAIT)
  PHASE(2, 0, NOSTAGE, NOWAIT)
  PHASE(3, 0, NOSTAGE, VM0)
  PHASE(0, 1, BVLOAD(1), NOWAIT)
  PHASE(1, 1, NOSTAGE, NOWAIT)
  PHASE(2, 1, NOSTAGE, NOWAIT)
  PHASE(3, 1, NOSTAGE, NOWAIT)

#pragma unroll
  for (int mi = 0; mi < 8; ++mi) {
#pragma unroll
    for (int ni = 0; ni < 4; ++ni) {
      const int col  = bn + wc * 64 + ni * 16 + lr;
      const int row0 = bm + wr * 128 + mi * 16 + quad * 4;
      const float bb = bias[col];
#pragma unroll
      for (int r = 0; r < 4; ++r) {
        float v = acc[mi][ni][r] + bb;
        v = fmaxf(v, 0.0f);
        obf[(size_t)(row0 + r) * N + col] = f2bf(v);
      }
    }
  }
}

// ---------------------------------------------------------------------------
// GEMM2: out[8192x1024] = resid + out1[8192x4096] @ woT^T
// R8: 256x128 tile, BK=64, 512 thr / 8 waves (4Mx2N, 64x64/wave), 96 KiB
// dbuf LDS (A 2x32KB, B 2x16KB), 2 phases/K-tile x 16 MFMA, counted VM2 at
// K-tile boundaries, grid 32x8=256 blocks = 1/CU, bijective XCD swizzle.
// A-tile = 2 pieces, B-tile = 1 piece; B(t+2) overwrites current buffer's B
// after register capture (BVLOAD) — same proven pattern as gemm1.
// ---------------------------------------------------------------------------
__global__ __launch_bounds__(512) void gemm2_kernel(
    const u16* __restrict__ A, const u16* __restrict__ Bt,
    const float* __restrict__ resid, float* __restrict__ out) {
  const int K = FDIM, N = DDIM;
  const int NT = K / 64;                    // 64 K-tiles
  const size_t KP = (size_t)128 * K;        // piece-1 global row offset
  __shared__ __align__(16) u16 sA[2][16384];  // 64 KB (2 bufs x 256x64)
  __shared__ __align__(16) u16 sB[2][8192];   // 32 KB (2 bufs x 128x64)

  const int tid  = threadIdx.x;
  const int lane = tid & 63;
  const int wave = tid >> 6;
  const int wr = wave >> 1, wc = wave & 1;    // 4 x 2 wave grid (64x64/wave)
  const int lr = lane & 15, quad = lane >> 4;

  // 256 blocks, 256 % 8 == 0 -> simple XCD swizzle is bijective.
  const int bid = blockIdx.x;
  const int swz = (bid & 7) * 32 + (bid >> 3);
  const int bm = (swz >> 3) * 256;
  const int bn = (swz & 7) * 128;

  int lofs0, lofs1;
  const u16 *gA0, *gA1, *gB0, *gB1;
  {
    const int s0 = tid,       r0 = s0 >> 3, g0 = (s0 & 7) ^ (r0 & 7);
    const int s1 = tid + 512, r1 = s1 >> 3, g1 = (s1 & 7) ^ (r1 & 7);
    gA0 = A  + (size_t)(bm + r0) * K + g0 * 8;
    gA1 = A  + (size_t)(bm + r1) * K + g1 * 8;
    gB0 = Bt + (size_t)(bn + r0) * K + g0 * 8;   // B rows 0..63 (slot tid)
    gB1 = Bt + (size_t)(bn + r1) * K + g1 * 8;   // B rows 64..127 (tid+512)
    lofs0 = s0 * 8; lofs1 = s1 * 8;
  }

  int arow8[4];
#pragma unroll
  for (int mi = 0; mi < 4; ++mi) arow8[mi] = (wr * 64 + mi * 16 + lr) * 8;
  const int brow80 = (wc * 64 +  0 + lr) * 8;
  const int brow81 = (wc * 64 + 16 + lr) * 8;
  const int brow82 = (wc * 64 + 32 + lr) * 8;
  const int brow83 = (wc * 64 + 48 + lr) * 8;
  const int sega0 = quad ^ (lr & 7);
  const int sega1 = (4 + quad) ^ (lr & 7);

  f32x4 acc[4][4] = {};
  bf16x8 bv[4][2];

  // prologue: B(0),A(0) -> buf0; B(1) -> buf1. VM2 leaves B(1) in flight.
  STAGE_B(0, 0, 0)
  STAGE_A(0, 0, 0) STAGE_A(0, 1, 0)
  STAGE_B(1, 0, 1)
  asm volatile("s_waitcnt vmcnt(2)" ::: "memory");
  __builtin_amdgcn_s_barrier();

  for (int tt = 0; tt < NT - 2; tt += 2) {
    // tiles tt (buf0) and tt+1 (buf1); 2 phases each
    PHASE(0, 0, BVLOAD(0); STAGE_A(tt + 1, 0, 1), NOWAIT)
    PHASE(1, 0, STAGE_A(tt + 1, 1, 1); STAGE_B(tt + 2, 0, 0), VM2)
    PHASE(0, 1, BVLOAD(1); STAGE_A(tt + 2, 0, 0), NOWAIT)
    PHASE(1, 1, STAGE_A(tt + 2, 1, 0); STAGE_B(tt + 3, 0, 1), VM2)
  }
  // tail: tiles NT-2 (buf0, stage last A tile) and NT-1 (buf1, compute only)
  PHASE(0, 0, BVLOAD(0); STAGE_A(NT - 1, 0, 1), NOWAIT)
  PHASE(1, 0, STAGE_A(NT - 1, 1, 1), VM0)
  PHASE(0, 1, BVLOAD(1), NOWAIT)
  PHASE(1, 1, NOSTAGE, NOWAIT)

  // epilogue: residual add, f32 store
#pragma unroll
  for (int mi = 0; mi < 4; ++mi) {
#pragma unroll
    for (int ni = 0; ni < 4; ++ni) {
      const int col  = bn + wc * 64 + ni * 16 + lr;
      const int row0 = bm + wr * 64 + mi * 16 + quad * 4;
#pragma unroll
      for (int r = 0; r < 4; ++r) {
        const size_t idx = (size_t)(row0 + r) * N + col;
        out[idx] = resid[idx] + acc[mi][ni][r];
      }
    }
  }
}

// ---------------------------------------------------------------------------
// Workspace layout (bytes):
//   hcat       [8192 x 3072] bf16              @ 0          (50331648)
//   WcatT      [4096 x 3072] bf16              @ 50331648   (25165824)
//   woT        [1024 x 4096] bf16              @ 75497472   ( 8388608)
//   out1       [8192 x 4096] bf16              @ 83886080   (67108864)
//     bucket_src [262144] i32 (aliases out1)   @ 83886080   ( 1048576)
//     cnt        [16384] i32                   @ 84934656   (   65536)
//     off        [16384] i32                   @ 85000192   (   65536)
//     cursor     [16384] i32                   @ 85065728   (   65536)
//     xq         [8192 x 1024] fp8             @ 85131264   ( 8388608)
//   (all aliased scratch consumed before GEMM1 writes out1)
// total: 150994944 bytes (144 MB)
// ---------------------------------------------------------------------------
extern "C" void kernel_launch(void* const* d_in, const int* in_sizes, int n_in,
                              void* d_out, int out_size, void* d_ws, size_t ws_size,
                              hipStream_t stream) {
  const float* hs     = (const float*)d_in[0];
  const float* weight = (const float*)d_in[1];   // [2,1024,4096]
  const float* root   = (const float*)d_in[2];   // [1024,4096]
  const float* bias   = (const float*)d_in[3];   // [4096]
  const float* wo     = (const float*)d_in[4];   // [4096,1024]
  const float* gamma  = (const float*)d_in[5];
  const float* beta   = (const float*)d_in[6];
  const int* edge_index = (const int*)d_in[7];   // [2,E]
  const int* edge_type  = (const int*)d_in[8];   // [E]
  float* out = (float*)d_out;

  char* ws = (char*)d_ws;
  u16*   hcat       = (u16*)(ws + 0);
  u16*   WcatT      = (u16*)(ws + 50331648);
  u16*   woT        = (u16*)(ws + 75497472);
  u16*   out1       = (u16*)(ws + 83886080);
  int*   bucket_src = (int*)(ws + 83886080);     // aliases out1 (consumed pre-GEMM1)
  int*   cnt        = (int*)(ws + 84934656);
  int*   off        = (int*)(ws + 85000192);
  int*   cursor     = (int*)(ws + 85065728);
  u32*   xq         = (u32*)(ws + 85131264);     // fp8 x, dense [8192][1024]

  (void)hipMemsetAsync(cnt, 0, 65536, stream);

  ln_kernel<<<NNODE, 256, 0, stream>>>(hs, gamma, beta, hcat, xq);

  cvt_transpose<<<dim3(FDIM / 32, KCAT / 32), dim3(32, 8), 0, stream>>>(
      weight, root, 2048, KCAT, FDIM, WcatT);
  cvt_transpose<<<dim3(DDIM / 32, FDIM / 32), dim3(32, 8), 0, stream>>>(
      wo, wo, FDIM, FDIM, DDIM, woT);

  count_kernel<<<E_NUM / 256, 256, 0, stream>>>(edge_index, edge_type, cnt);
  scan_kernel<<<1, 1024, 0, stream>>>(cnt, off, cursor);
  fill_kernel<<<E_NUM / 256, 256, 0, stream>>>(edge_index, edge_type, cursor, bucket_src);
  aggregate_kernel<<<NBKT, 256, 0, stream>>>(cnt, off, bucket_src, xq, hcat);

  // out1 = relu([h0|h1|x] @ [W0;W1;root] + bias)   [8192 x 4096] bf16
  gemm1_kernel<<<512, 512, 0, stream>>>(hcat, WcatT, bias, out1);

  // out = hs + out1 @ wo                            [8192 x 1024] f32
  gemm2_kernel<<<256, 512, 0, stream>>>(out1, woT, hs, out);
}